// Round 6
// baseline (847.691 us; speedup 1.0000x reference)
//
#include <hip/hip_runtime.h>
#include <stdint.h>
#include <cmath>

typedef unsigned short u16;
typedef _Float16 f16;
typedef f16   f16x8 __attribute__((ext_vector_type(8)));
typedef float f32x4 __attribute__((ext_vector_type(4)));
typedef u16   u16x8 __attribute__((ext_vector_type(8)));

#define GLD16(gsrc, ldst)                                                      \
  __builtin_amdgcn_global_load_lds(                                            \
      (__attribute__((address_space(1))) void*)(gsrc),                         \
      (__attribute__((address_space(3))) void*)(ldst), 16, 0, 0)

__device__ __forceinline__ u16 f2h(float x) {
  f16 h = (f16)x;
  return __builtin_bit_cast(u16, h);
}

__device__ __forceinline__ f32x4 mfma16(f16x8 a, f16x8 b, f32x4 c) {
  return __builtin_amdgcn_mfma_f32_16x16x32_f16(a, b, c, 0, 0, 0);
}

// ---------------- f32 -> f16 convert (vectorized, 8 elems/thread/iter) ------
__global__ void cvt_f32_f16(const float* __restrict__ in, u16* __restrict__ out,
                            long n8) {
  long i = (long)blockIdx.x * 256 + threadIdx.x;
  const long stride = (long)gridDim.x * 256;
  for (; i < n8; i += stride) {
    const float4* p = (const float4*)in + 2 * i;
    float4 a = p[0], b = p[1];
    u16x8 o;
    o[0] = f2h(a.x); o[1] = f2h(a.y); o[2] = f2h(a.z); o[3] = f2h(a.w);
    o[4] = f2h(b.x); o[5] = f2h(b.y); o[6] = f2h(b.z); o[7] = f2h(b.w);
    *((u16x8*)out + i) = o;
  }
}

// ========== 256x256 overlap-pipelined GEMM  C[M,N] = A[M,K]*B[N,K]^T ========
// 512 threads = 8 waves (2M x 4N), wave tile 128x64, 16x16x32 MFMA.
// BK=32, 4 LDS buffers x 32KB. ONE barrier + ONE counted vmcnt(4) per K-tile.
// ds_reads overlap MFMA: phase-B A-frags read before MFMA-A; next tile's
// phase-A frags read before MFMA-B. Compiler manages lgkmcnt per-use (no
// asm lgkm drain, no sched_barrier pinning).
// LDS swizzle (verified 0-conflict r3): row pairs -> 128B lines,
// inner ^= ((line&7)<<4). Requires M%256==0, N%256==0, K%32==0, K/32>=4.

__device__ __forceinline__ int swz_addr(int r, int ckbyte) {
  int line = r >> 1;
  return line * 128 + ((((r & 1) << 6) | ckbyte) ^ ((line & 7) << 4));
}

template <int OUT_F16, int HAS_BIAS>
__global__ __launch_bounds__(512, 2) void gemm_pipe(const u16* __restrict__ A,
                                                    const u16* __restrict__ B,
                                                    void* __restrict__ Cp,
                                                    const float* __restrict__ bias,
                                                    int M, int N, int K) {
  extern __shared__ char smem[];  // 4 x 32768; per buf: A @0 (16KB), B @16384
  const int tid = threadIdx.x;
  const int lane = tid & 63, wid = tid >> 6;
  const int wm = wid >> 2, wn = wid & 3;  // 2 x 4 waves
  const int lq = lane >> 4, lr = lane & 15;

  // ---- bijective XCD swizzle (m204) ----
  int nwg = gridDim.x;
  int orig = blockIdx.x;
  int q8 = nwg >> 3, r8 = nwg & 7;
  int xcd = orig & 7, idx = orig >> 3;
  int wg = (xcd < r8 ? xcd * (q8 + 1) : r8 * (q8 + 1) + (xcd - r8) * q8) + idx;
  const int gn = N >> 8;
  const int mb = wg / gn, nb = wg % gn;
  const int m0 = mb * 256, n0 = nb * 256;

  const int NT = K >> 5;  // K-tiles of 32

  // ---- per-thread staging source decode (inverse swizzle on global src) ----
  int offs[2];
  offs[0] = wid * 1024 + lane * 16;
  offs[1] = offs[0] + 8192;
  const u16* srcA[2];
  const u16* srcB[2];
#pragma unroll
  for (int is = 0; is < 2; ++is) {
    int off = offs[is];
    int line = off >> 7;
    int j2 = (off & 127) ^ ((line & 7) << 4);
    int r = 2 * line + (j2 >> 6), ck = j2 & 63;
    srcA[is] = A + (size_t)(m0 + r) * K + (ck >> 1);
    srcB[is] = B + (size_t)(n0 + r) * K + (ck >> 1);
  }

#define STAGE(t)                                                              \
  do {                                                                        \
    char* db = smem + ((t) & 3) * 32768 + wid * 1024;                         \
    GLD16(srcA[0] + (size_t)(t) * 32, db);                                    \
    GLD16(srcA[1] + (size_t)(t) * 32, db + 8192);                             \
    GLD16(srcB[0] + (size_t)(t) * 32, db + 16384);                            \
    GLD16(srcB[1] + (size_t)(t) * 32, db + 24576);                            \
  } while (0)

  // ---- fragment LDS addresses (swizzled) ----
  int addrA[8], addrB[4];
#pragma unroll
  for (int m = 0; m < 8; ++m)
    addrA[m] = swz_addr(wm * 128 + m * 16 + lr, lq * 16);
#pragma unroll
  for (int n = 0; n < 4; ++n)
    addrB[n] = 16384 + swz_addr(wn * 64 + n * 16 + lr, lq * 16);

  f32x4 acc[8][4] = {};

  // ---- prologue: stage tiles 0,1,2; ensure 0 and 1 landed ----
  STAGE(0);
  STAGE(1);
  STAGE(2);
  asm volatile("s_waitcnt vmcnt(4)" ::: "memory");  // t0,t1 landed (own loads)
  __builtin_amdgcn_s_barrier();                     // everyone's loads landed

  // preload phase-A fragments of tile 0
  f16x8 bfr[4], afr[4];
  {
    const char* b0 = smem;
#pragma unroll
    for (int n = 0; n < 4; ++n) bfr[n] = *(const f16x8*)(b0 + addrB[n]);
#pragma unroll
    for (int m = 0; m < 4; ++m) afr[m] = *(const f16x8*)(b0 + addrA[m]);
  }

  for (int t = 0; t < NT; ++t) {
    const char* cur = smem + (t & 3) * 32768;
    const char* nxt = smem + ((t + 1) & 3) * 32768;

    // early reads: phase-B A-frags from cur (complete under MFMA-A)
    f16x8 afr2[4];
#pragma unroll
    for (int m = 0; m < 4; ++m) afr2[m] = *(const f16x8*)(cur + addrA[4 + m]);

    if (t + 3 < NT) STAGE(t + 3);  // uniform branch

    // ===== MFMA phase A (uses preloaded afr/bfr) =====
    __builtin_amdgcn_s_setprio(1);
#pragma unroll
    for (int m = 0; m < 4; ++m)
#pragma unroll
      for (int n = 0; n < 4; ++n)
        acc[m][n] = mfma16(afr[m], bfr[n], acc[m][n]);
    __builtin_amdgcn_s_setprio(0);

    // reads for next tile's phase A (complete under MFMA-B)
    f16x8 nbfr[4], nafr[4];
#pragma unroll
    for (int n = 0; n < 4; ++n) nbfr[n] = *(const f16x8*)(nxt + addrB[n]);
#pragma unroll
    for (int m = 0; m < 4; ++m) nafr[m] = *(const f16x8*)(nxt + addrA[m]);

    // ===== MFMA phase B (B-frags reused from registers) =====
    __builtin_amdgcn_s_setprio(1);
#pragma unroll
    for (int m = 0; m < 4; ++m)
#pragma unroll
      for (int n = 0; n < 4; ++n)
        acc[4 + m][n] = mfma16(afr2[m], bfr[n], acc[4 + m][n]);
    __builtin_amdgcn_s_setprio(0);

    // rotate register double-buffer
#pragma unroll
    for (int n = 0; n < 4; ++n) bfr[n] = nbfr[n];
#pragma unroll
    for (int m = 0; m < 4; ++m) afr[m] = nafr[m];

    // boundary: tile t+2 must be fully landed before tile t+1 reads it.
    // steady state: outstanding = t+3's 4 loads -> counted vmcnt(4).
    if (t + 3 < NT)
      asm volatile("s_waitcnt vmcnt(4)" ::: "memory");
    else
      asm volatile("s_waitcnt vmcnt(0)" ::: "memory");
    __builtin_amdgcn_s_barrier();
  }
#undef STAGE

  // ---- epilogue ----
  const int mbase = m0 + wm * 128, nbase = n0 + wn * 64;
  float bv[4];
#pragma unroll
  for (int n = 0; n < 4; ++n)
    bv[n] = HAS_BIAS ? bias[nbase + n * 16 + lr] : 0.0f;
#pragma unroll
  for (int m = 0; m < 8; ++m) {
#pragma unroll
    for (int r = 0; r < 4; ++r) {
      int grow = mbase + m * 16 + lq * 4 + r;
#pragma unroll
      for (int n = 0; n < 4; ++n) {
        int gcol = nbase + n * 16 + lr;
        float v = acc[m][n][r] + bv[n];
        if (OUT_F16)
          ((u16*)Cp)[(size_t)grow * N + gcol] = f2h(v);
        else
          ((float*)Cp)[(size_t)grow * N + gcol] = v;
      }
    }
  }
}

// ---------------- small GEMM (K/V projections, M=1232 w/ tail) --------------
template <int OUT_F16, int HAS_BIAS, int MTAIL>
__global__ __launch_bounds__(256) void gemm_bt(const u16* __restrict__ A,
                                               const u16* __restrict__ B,
                                               void* __restrict__ Cp,
                                               const float* __restrict__ bias,
                                               int M, int N, int K) {
  constexpr int BK = 64;
  __shared__ u16 Asm[128 * BK];
  __shared__ u16 Bsm[128 * BK];
  const int tid = threadIdx.x;
  const int lane = tid & 63, wid = tid >> 6;
  const int wm = wid >> 1, wn = wid & 1;
  const int m0 = blockIdx.y * 128, n0 = blockIdx.x * 128;
  const int lq = lane >> 4, lr = lane & 15;
  const int koff = lq << 3;

  f32x4 acc[4][4] = {};

  for (int k0 = 0; k0 < K; k0 += BK) {
#pragma unroll
    for (int j = 0; j < 4; ++j) {
      int off = (wid * 4 + j) * 1024 + lane * 16;
      int r = off >> 7;
      int c = (off & 127) >> 1;
      int gr = m0 + r;
      if (MTAIL) gr = gr < M ? gr : M - 1;
      GLD16(A + (size_t)gr * K + k0 + c, (char*)Asm + (wid * 4 + j) * 1024);
    }
#pragma unroll
    for (int j = 0; j < 4; ++j) {
      int off = (wid * 4 + j) * 1024 + lane * 16;
      int r = off >> 7;
      int c = (off & 127) >> 1;
      GLD16(B + (size_t)(n0 + r) * K + k0 + c, (char*)Bsm + (wid * 4 + j) * 1024);
    }
    __syncthreads();
#pragma unroll
    for (int ks = 0; ks < 2; ++ks) {
      f16x8 af[4], bfr[4];
#pragma unroll
      for (int m = 0; m < 4; ++m)
        af[m] = *(const f16x8*)(Asm + (wm * 64 + m * 16 + lr) * BK + ks * 32 + koff);
#pragma unroll
      for (int n = 0; n < 4; ++n)
        bfr[n] = *(const f16x8*)(Bsm + (wn * 64 + n * 16 + lr) * BK + ks * 32 + koff);
#pragma unroll
      for (int m = 0; m < 4; ++m)
#pragma unroll
        for (int n = 0; n < 4; ++n)
          acc[m][n] = mfma16(af[m], bfr[n], acc[m][n]);
    }
    __syncthreads();
  }

#pragma unroll
  for (int m = 0; m < 4; ++m) {
#pragma unroll
    for (int r = 0; r < 4; ++r) {
      int grow = m0 + wm * 64 + m * 16 + lq * 4 + r;
      if (MTAIL && grow >= M) continue;
#pragma unroll
      for (int n = 0; n < 4; ++n) {
        int gcol = n0 + wn * 64 + n * 16 + lr;
        float v = acc[m][n][r];
        if (HAS_BIAS) v += bias[gcol];
        if (OUT_F16)
          ((u16*)Cp)[(size_t)grow * N + gcol] = f2h(v);
        else
          ((float*)Cp)[(size_t)grow * N + gcol] = v;
      }
    }
  }
}

// ---------------- fused attention ------------------------------------------
__global__ __launch_bounds__(256) void attn_fused(const u16* __restrict__ Q,
                                                  const u16* __restrict__ Kp,
                                                  const u16* __restrict__ Vp,
                                                  u16* __restrict__ Oa,
                                                  float scale) {
  __shared__ u16 Ksm[80][168];
  __shared__ u16 VT[160][104];
  __shared__ u16 Psm[4][16][96];
  const int tid = threadIdx.x, lane = tid & 63, wid = tid >> 6;
  const int lq = lane >> 4, lr = lane & 15, koff = lq << 3;
  const int qt = blockIdx.x, h = blockIdx.y, b = blockIdx.z;

  {
    u16x8 z = {0, 0, 0, 0, 0, 0, 0, 0};
    for (int i = tid; i < 80 * 168 / 8; i += 256) ((u16x8*)&Ksm[0][0])[i] = z;
    for (int i = tid; i < 160 * 104 / 8; i += 256) ((u16x8*)&VT[0][0])[i] = z;
    for (int i = tid; i < 4 * 16 * 96 / 8; i += 256) ((u16x8*)&Psm[0][0][0])[i] = z;
  }
  __syncthreads();

  const size_t kvbase = ((size_t)b * 77) * 1280 + (size_t)h * 160;
  for (int i = tid; i < 77 * 20; i += 256) {
    int r = i / 20, c8 = (i % 20) * 8;
    *(u16x8*)&Ksm[r][c8] = *(const u16x8*)(Kp + kvbase + (size_t)r * 1280 + c8);
  }
  for (int i = tid; i < 77 * 20; i += 256) {
    int r = i / 20, c8 = (i % 20) * 8;
    u16x8 v = *(const u16x8*)(Vp + kvbase + (size_t)r * 1280 + c8);
#pragma unroll
    for (int j = 0; j < 8; ++j) VT[c8 + j][r] = v[j];
  }

  f16x8 qf[5];
  const int qrow = qt * 64 + wid * 16 + lr;
  const size_t qbase = ((size_t)b * 4096 + qrow) * 1280 + (size_t)h * 160;
#pragma unroll
  for (int ks = 0; ks < 5; ++ks)
    qf[ks] = *(const f16x8*)(Q + qbase + ks * 32 + koff);
  __syncthreads();

  f32x4 sc[5];
#pragma unroll
  for (int nt = 0; nt < 5; ++nt) {
    sc[nt] = (f32x4){0.f, 0.f, 0.f, 0.f};
#pragma unroll
    for (int ks = 0; ks < 5; ++ks) {
      f16x8 kf = *(const f16x8*)&Ksm[nt * 16 + lr][ks * 32 + koff];
      sc[nt] = mfma16(qf[ks], kf, sc[nt]);
    }
  }

  float p[5][4];
#pragma unroll
  for (int r = 0; r < 4; ++r) {
    float mx = -1e30f;
#pragma unroll
    for (int nt = 0; nt < 5; ++nt) {
      float v = sc[nt][r] * scale;
      if (nt * 16 + lr >= 77) v = -1e30f;
      p[nt][r] = v;
      mx = fmaxf(mx, v);
    }
#pragma unroll
    for (int d = 1; d < 16; d <<= 1) mx = fmaxf(mx, __shfl_xor(mx, d));
    float sum = 0.f;
#pragma unroll
    for (int nt = 0; nt < 5; ++nt) {
      float e = __expf(p[nt][r] - mx);
      p[nt][r] = e;
      sum += e;
    }
#pragma unroll
    for (int d = 1; d < 16; d <<= 1) sum += __shfl_xor(sum, d);
    float inv = 1.f / sum;
#pragma unroll
    for (int nt = 0; nt < 5; ++nt) p[nt][r] *= inv;
  }

#pragma unroll
  for (int r = 0; r < 4; ++r)
#pragma unroll
    for (int nt = 0; nt < 5; ++nt)
      Psm[wid][lq * 4 + r][nt * 16 + lr] = f2h(p[nt][r]);

  f32x4 ov[10];
#pragma unroll
  for (int n2 = 0; n2 < 10; ++n2) ov[n2] = (f32x4){0.f, 0.f, 0.f, 0.f};
#pragma unroll
  for (int k2 = 0; k2 < 3; ++k2) {
    f16x8 pf = *(const f16x8*)&Psm[wid][lr][k2 * 32 + koff];
#pragma unroll
    for (int n2 = 0; n2 < 10; ++n2) {
      f16x8 vf = *(const f16x8*)&VT[n2 * 16 + lr][k2 * 32 + koff];
      ov[n2] = mfma16(pf, vf, ov[n2]);
    }
  }

  const size_t obase =
      ((size_t)b * 4096 + (size_t)qt * 64 + wid * 16 + lq * 4) * 1280 +
      (size_t)h * 160;
#pragma unroll
  for (int r = 0; r < 4; ++r)
#pragma unroll
    for (int n2 = 0; n2 < 10; ++n2)
      Oa[obase + (size_t)r * 1280 + n2 * 16 + lr] = f2h(ov[n2][r]);
}

// ---------------- host orchestration ----------------------------------------
extern "C" void kernel_launch(void* const* d_in, const int* in_sizes, int n_in,
                              void* d_out, int out_size, void* d_ws,
                              size_t ws_size, hipStream_t stream) {
  (void)in_sizes; (void)n_in; (void)out_size; (void)ws_size;
  const float* hs  = (const float*)d_in[0];
  const float* enc = (const float*)d_in[1];
  const float* Wq  = (const float*)d_in[2];
  const float* Wk  = (const float*)d_in[3];
  const float* Wv  = (const float*)d_in[4];
  const float* Wo  = (const float*)d_in[5];
  const float* bo  = (const float*)d_in[6];
  float* out = (float*)d_out;

  const int B = 16, S = 4096, SKV = 77, HID = 1280, CDIM = 768;
  const int MQ = B * S;
  const int MKV = B * SKV;

  char* ws = (char*)d_ws;
  size_t off = 0;
  auto alloc = [&](size_t bytes) -> char* {
    char* p = ws + off;
    off += (bytes + 255) & ~(size_t)255;
    return p;
  };
  u16* hs_h  = (u16*)alloc((size_t)MQ * HID * 2);
  u16* q_h   = (u16*)alloc((size_t)MQ * HID * 2);
  u16* enc_h = (u16*)alloc((size_t)MKV * CDIM * 2);
  u16* wq_h  = (u16*)alloc((size_t)HID * HID * 2);
  u16* wk_h  = (u16*)alloc((size_t)HID * CDIM * 2);
  u16* wv_h  = (u16*)alloc((size_t)HID * CDIM * 2);
  u16* wo_h  = (u16*)alloc((size_t)HID * HID * 2);
  u16* k_h   = (u16*)alloc((size_t)MKV * HID * 2);
  u16* v_h   = (u16*)alloc((size_t)MKV * HID * 2);
  u16* attn_h = hs_h;  // hs_h dead after Q projection

  auto cvt = [&](const float* src, u16* dst, long n) {
    long n8 = n / 8;
    int blocks = (int)((n8 + 255) / 256);
    if (blocks > 2048) blocks = 2048;
    cvt_f32_f16<<<blocks, 256, 0, stream>>>(src, dst, n8);
  };
  cvt(hs,  hs_h,  (long)MQ * HID);
  cvt(enc, enc_h, (long)MKV * CDIM);
  cvt(Wq,  wq_h,  (long)HID * HID);
  cvt(Wk,  wk_h,  (long)HID * CDIM);
  cvt(Wv,  wv_h,  (long)HID * CDIM);
  cvt(Wo,  wo_h,  (long)HID * HID);

  // K/V projections (small, tail): 128^2 kernel
  gemm_bt<1, 0, 1><<<dim3(10, 10), 256, 0, stream>>>(enc_h, wk_h, k_h, nullptr, MKV, HID, CDIM);
  gemm_bt<1, 0, 1><<<dim3(10, 10), 256, 0, stream>>>(enc_h, wv_h, v_h, nullptr, MKV, HID, CDIM);

  // Q projection: 256^2 overlap-pipelined kernel. grid = (M/256)*(N/256)
  const int grid_big = (MQ / 256) * (HID / 256);
  gemm_pipe<1, 0><<<dim3(grid_big), dim3(512), 131072, stream>>>(
      hs_h, wq_h, q_h, nullptr, MQ, HID, HID);

  const float scale = 1.0f / sqrtf(160.0f);
  attn_fused<<<dim3(64, 8, 16), 256, 0, stream>>>(q_h, k_h, v_h, attn_h, scale);

  // output projection (+bias, f32 out)
  gemm_pipe<0, 1><<<dim3(grid_big), dim3(512), 131072, stream>>>(
      attn_h, wo_h, out, bo, MQ, HID, HID);
}

// Round 7
// 835.371 us; speedup vs baseline: 1.0147x; 1.0147x over previous
//
#include <hip/hip_runtime.h>
#include <stdint.h>
#include <cmath>

typedef unsigned short u16;
typedef _Float16 f16;
typedef f16   f16x8 __attribute__((ext_vector_type(8)));
typedef float f32x4 __attribute__((ext_vector_type(4)));
typedef u16   u16x8 __attribute__((ext_vector_type(8)));

#define GLD16(gsrc, ldst)                                                      \
  __builtin_amdgcn_global_load_lds(                                            \
      (__attribute__((address_space(1))) void*)(gsrc),                         \
      (__attribute__((address_space(3))) void*)(ldst), 16, 0, 0)

__device__ __forceinline__ u16 f2h(float x) {
  f16 h = (f16)x;
  return __builtin_bit_cast(u16, h);
}

__device__ __forceinline__ f32x4 mfma16(f16x8 a, f16x8 b, f32x4 c) {
  return __builtin_amdgcn_mfma_f32_16x16x32_f16(a, b, c, 0, 0, 0);
}

// ---------------- f32 -> f16 convert (vectorized, 8 elems/thread/iter) ------
__global__ void cvt_f32_f16(const float* __restrict__ in, u16* __restrict__ out,
                            long n8) {
  long i = (long)blockIdx.x * 256 + threadIdx.x;
  const long stride = (long)gridDim.x * 256;
  for (; i < n8; i += stride) {
    const float4* p = (const float4*)in + 2 * i;
    float4 a = p[0], b = p[1];
    u16x8 o;
    o[0] = f2h(a.x); o[1] = f2h(a.y); o[2] = f2h(a.z); o[3] = f2h(a.w);
    o[4] = f2h(b.x); o[5] = f2h(b.y); o[6] = f2h(b.z); o[7] = f2h(b.w);
    *((u16x8*)out + i) = o;
  }
}

// ================= 256x256 pipelined GEMM  C[M,N] = A[M,K]*B[N,K]^T =========
// 512 threads = 8 waves (2M x 4N). BK=32, 4 LDS buffers (4 x 32KB = 128 KiB).
// Steady-state counted vmcnt(8): prefetch K-tile c+3 while computing c.
// LDS swizzle: rows paired into 128B lines; inner ^= ((line&7)<<4).
// r7 = r3 minus sched_barrier(0) order-pinning (m141 hypothesis test).

__device__ __forceinline__ int swz_addr(int r, int ckbyte) {
  int line = r >> 1;
  return line * 128 + ((((r & 1) << 6) | ckbyte) ^ ((line & 7) << 4));
}

template <int OUT_F16, int HAS_BIAS>
__global__ __launch_bounds__(512, 2) void gemm_bt8(const u16* __restrict__ A,
                                                   const u16* __restrict__ B,
                                                   void* __restrict__ Cp,
                                                   const float* __restrict__ bias,
                                                   int M, int N, int K) {
  extern __shared__ char smem[];  // 131072 bytes: buf q at q*32768; A then B
  const int tid = threadIdx.x;
  const int lane = tid & 63, wid = tid >> 6;
  const int wm = wid >> 2, wn = wid & 3;  // 2 x 4 waves
  const int lq = lane >> 4, lr = lane & 15;

  // ---- bijective XCD swizzle (m204) ----
  int nwg = gridDim.x;
  int orig = blockIdx.x;
  int q8 = nwg >> 3, r8 = nwg & 7;
  int xcd = orig & 7, idx = orig >> 3;
  int wg = (xcd < r8 ? xcd * (q8 + 1) : r8 * (q8 + 1) + (xcd - r8) * q8) + idx;
  const int gn = N >> 8;
  const int mb = wg / gn, nb = wg % gn;
  const int m0 = mb * 256, n0 = nb * 256;

  const int NT = K >> 5;  // K-tiles of 32

  // ---- per-thread staging source decode (inverse swizzle on global src) ----
  int offs[2];
  offs[0] = wid * 1024 + lane * 16;
  offs[1] = offs[0] + 8192;
  const u16* srcA[2];
  const u16* srcB[2];
#pragma unroll
  for (int is = 0; is < 2; ++is) {
    int off = offs[is];
    int line = off >> 7;
    int j2 = (off & 127) ^ ((line & 7) << 4);
    int r = 2 * line + (j2 >> 6), ck = j2 & 63;
    srcA[is] = A + (size_t)(m0 + r) * K + (ck >> 1);
    srcB[is] = B + (size_t)(n0 + r) * K + (ck >> 1);
  }

#define GLDA(t)                                                               \
  do {                                                                        \
    char* db = smem + ((t) & 3) * 32768 + wid * 1024;                         \
    GLD16(srcA[0] + (size_t)(t) * 32, db);                                    \
    GLD16(srcA[1] + (size_t)(t) * 32, db + 8192);                             \
  } while (0)
#define GLDB(t)                                                               \
  do {                                                                        \
    char* db = smem + ((t) & 3) * 32768 + 16384 + wid * 1024;                 \
    GLD16(srcB[0] + (size_t)(t) * 32, db);                                    \
    GLD16(srcB[1] + (size_t)(t) * 32, db + 8192);                             \
  } while (0)

  // ---- fragment LDS addresses (swizzled) ----
  int addrA[8], addrB[4];
#pragma unroll
  for (int m = 0; m < 8; ++m)
    addrA[m] = swz_addr(wm * 128 + m * 16 + lr, lq * 16);
#pragma unroll
  for (int n = 0; n < 4; ++n)
    addrB[n] = 16384 + swz_addr(wn * 64 + n * 16 + lr, lq * 16);

  f32x4 acc[8][4] = {};

  // ---- prologue: prefetch K-tiles 0,1,2 ----
#pragma unroll
  for (int t = 0; t < 3; ++t) {
    GLDA(t);
    GLDB(t);
  }
  asm volatile("s_waitcnt vmcnt(8)" ::: "memory");  // tile 0 landed (own share)
  __builtin_amdgcn_s_barrier();                     // all waves' shares landed

  for (int c = 0; c < NT; ++c) {
    const char* bb = smem + (c & 3) * 32768;
    const int pf = c + 3;
    // ================= phase A: quadrant m0..3, full K=32 ==================
    f16x8 bfr[4], afr[4];
#pragma unroll
    for (int n = 0; n < 4; ++n) bfr[n] = *(const f16x8*)(bb + addrB[n]);
#pragma unroll
    for (int m = 0; m < 4; ++m) afr[m] = *(const f16x8*)(bb + addrA[m]);
    if (pf < NT) GLDA(pf);  // uniform branch
    __builtin_amdgcn_s_barrier();
    asm volatile("s_waitcnt lgkmcnt(0)" ::: "memory");
    __builtin_amdgcn_s_setprio(1);
#pragma unroll
    for (int m = 0; m < 4; ++m)
#pragma unroll
      for (int n = 0; n < 4; ++n)
        acc[m][n] = mfma16(afr[m], bfr[n], acc[m][n]);
    __builtin_amdgcn_s_setprio(0);
    __builtin_amdgcn_s_barrier();
    // ================= phase B: quadrant m4..7 (B-frags reused) ============
    f16x8 afr2[4];
#pragma unroll
    for (int m = 0; m < 4; ++m) afr2[m] = *(const f16x8*)(bb + addrA[4 + m]);
    if (pf < NT) GLDB(pf);
    // boundary: ensure K-tile c+1's loads landed; keep c+2/c+3 in flight
    if (c + 3 < NT)
      asm volatile("s_waitcnt vmcnt(8)" ::: "memory");
    else if (c + 2 < NT)
      asm volatile("s_waitcnt vmcnt(4)" ::: "memory");
    else if (c + 1 < NT)
      asm volatile("s_waitcnt vmcnt(0)" ::: "memory");
    __builtin_amdgcn_s_barrier();
    asm volatile("s_waitcnt lgkmcnt(0)" ::: "memory");
    __builtin_amdgcn_s_setprio(1);
#pragma unroll
    for (int m = 0; m < 4; ++m)
#pragma unroll
      for (int n = 0; n < 4; ++n)
        acc[4 + m][n] = mfma16(afr2[m], bfr[n], acc[4 + m][n]);
    __builtin_amdgcn_s_setprio(0);
    __builtin_amdgcn_s_barrier();
  }
#undef GLDA
#undef GLDB

  // ---- epilogue ----
  const int mbase = m0 + wm * 128, nbase = n0 + wn * 64;
  float bv[4];
#pragma unroll
  for (int n = 0; n < 4; ++n)
    bv[n] = HAS_BIAS ? bias[nbase + n * 16 + lr] : 0.0f;
#pragma unroll
  for (int m = 0; m < 8; ++m) {
#pragma unroll
    for (int r = 0; r < 4; ++r) {
      int grow = mbase + m * 16 + lq * 4 + r;
#pragma unroll
      for (int n = 0; n < 4; ++n) {
        int gcol = nbase + n * 16 + lr;
        float v = acc[m][n][r] + bv[n];
        if (OUT_F16)
          ((u16*)Cp)[(size_t)grow * N + gcol] = f2h(v);
        else
          ((float*)Cp)[(size_t)grow * N + gcol] = v;
      }
    }
  }
}

// ---------------- small GEMM (K/V projections, M=1232 w/ tail) --------------
template <int OUT_F16, int HAS_BIAS, int MTAIL>
__global__ __launch_bounds__(256) void gemm_bt(const u16* __restrict__ A,
                                               const u16* __restrict__ B,
                                               void* __restrict__ Cp,
                                               const float* __restrict__ bias,
                                               int M, int N, int K) {
  constexpr int BK = 64;
  __shared__ u16 Asm[128 * BK];
  __shared__ u16 Bsm[128 * BK];
  const int tid = threadIdx.x;
  const int lane = tid & 63, wid = tid >> 6;
  const int wm = wid >> 1, wn = wid & 1;
  const int m0 = blockIdx.y * 128, n0 = blockIdx.x * 128;
  const int lq = lane >> 4, lr = lane & 15;
  const int koff = lq << 3;

  f32x4 acc[4][4] = {};

  for (int k0 = 0; k0 < K; k0 += BK) {
#pragma unroll
    for (int j = 0; j < 4; ++j) {
      int off = (wid * 4 + j) * 1024 + lane * 16;
      int r = off >> 7;
      int c = (off & 127) >> 1;
      int gr = m0 + r;
      if (MTAIL) gr = gr < M ? gr : M - 1;
      GLD16(A + (size_t)gr * K + k0 + c, (char*)Asm + (wid * 4 + j) * 1024);
    }
#pragma unroll
    for (int j = 0; j < 4; ++j) {
      int off = (wid * 4 + j) * 1024 + lane * 16;
      int r = off >> 7;
      int c = (off & 127) >> 1;
      GLD16(B + (size_t)(n0 + r) * K + k0 + c, (char*)Bsm + (wid * 4 + j) * 1024);
    }
    __syncthreads();
#pragma unroll
    for (int ks = 0; ks < 2; ++ks) {
      f16x8 af[4], bfr[4];
#pragma unroll
      for (int m = 0; m < 4; ++m)
        af[m] = *(const f16x8*)(Asm + (wm * 64 + m * 16 + lr) * BK + ks * 32 + koff);
#pragma unroll
      for (int n = 0; n < 4; ++n)
        bfr[n] = *(const f16x8*)(Bsm + (wn * 64 + n * 16 + lr) * BK + ks * 32 + koff);
#pragma unroll
      for (int m = 0; m < 4; ++m)
#pragma unroll
        for (int n = 0; n < 4; ++n)
          acc[m][n] = mfma16(af[m], bfr[n], acc[m][n]);
    }
    __syncthreads();
  }

#pragma unroll
  for (int m = 0; m < 4; ++m) {
#pragma unroll
    for (int r = 0; r < 4; ++r) {
      int grow = m0 + wm * 64 + m * 16 + lq * 4 + r;
      if (MTAIL && grow >= M) continue;
#pragma unroll
      for (int n = 0; n < 4; ++n) {
        int gcol = n0 + wn * 64 + n * 16 + lr;
        float v = acc[m][n][r];
        if (HAS_BIAS) v += bias[gcol];
        if (OUT_F16)
          ((u16*)Cp)[(size_t)grow * N + gcol] = f2h(v);
        else
          ((float*)Cp)[(size_t)grow * N + gcol] = v;
      }
    }
  }
}

// ---------------- fused attention ------------------------------------------
__global__ __launch_bounds__(256) void attn_fused(const u16* __restrict__ Q,
                                                  const u16* __restrict__ Kp,
                                                  const u16* __restrict__ Vp,
                                                  u16* __restrict__ Oa,
                                                  float scale) {
  __shared__ u16 Ksm[80][168];
  __shared__ u16 VT[160][104];
  __shared__ u16 Psm[4][16][96];
  const int tid = threadIdx.x, lane = tid & 63, wid = tid >> 6;
  const int lq = lane >> 4, lr = lane & 15, koff = lq << 3;
  const int qt = blockIdx.x, h = blockIdx.y, b = blockIdx.z;

  {
    u16x8 z = {0, 0, 0, 0, 0, 0, 0, 0};
    for (int i = tid; i < 80 * 168 / 8; i += 256) ((u16x8*)&Ksm[0][0])[i] = z;
    for (int i = tid; i < 160 * 104 / 8; i += 256) ((u16x8*)&VT[0][0])[i] = z;
    for (int i = tid; i < 4 * 16 * 96 / 8; i += 256) ((u16x8*)&Psm[0][0][0])[i] = z;
  }
  __syncthreads();

  const size_t kvbase = ((size_t)b * 77) * 1280 + (size_t)h * 160;
  for (int i = tid; i < 77 * 20; i += 256) {
    int r = i / 20, c8 = (i % 20) * 8;
    *(u16x8*)&Ksm[r][c8] = *(const u16x8*)(Kp + kvbase + (size_t)r * 1280 + c8);
  }
  for (int i = tid; i < 77 * 20; i += 256) {
    int r = i / 20, c8 = (i % 20) * 8;
    u16x8 v = *(const u16x8*)(Vp + kvbase + (size_t)r * 1280 + c8);
#pragma unroll
    for (int j = 0; j < 8; ++j) VT[c8 + j][r] = v[j];
  }

  f16x8 qf[5];
  const int qrow = qt * 64 + wid * 16 + lr;
  const size_t qbase = ((size_t)b * 4096 + qrow) * 1280 + (size_t)h * 160;
#pragma unroll
  for (int ks = 0; ks < 5; ++ks)
    qf[ks] = *(const f16x8*)(Q + qbase + ks * 32 + koff);
  __syncthreads();

  f32x4 sc[5];
#pragma unroll
  for (int nt = 0; nt < 5; ++nt) {
    sc[nt] = (f32x4){0.f, 0.f, 0.f, 0.f};
#pragma unroll
    for (int ks = 0; ks < 5; ++ks) {
      f16x8 kf = *(const f16x8*)&Ksm[nt * 16 + lr][ks * 32 + koff];
      sc[nt] = mfma16(qf[ks], kf, sc[nt]);
    }
  }

  float p[5][4];
#pragma unroll
  for (int r = 0; r < 4; ++r) {
    float mx = -1e30f;
#pragma unroll
    for (int nt = 0; nt < 5; ++nt) {
      float v = sc[nt][r] * scale;
      if (nt * 16 + lr >= 77) v = -1e30f;
      p[nt][r] = v;
      mx = fmaxf(mx, v);
    }
#pragma unroll
    for (int d = 1; d < 16; d <<= 1) mx = fmaxf(mx, __shfl_xor(mx, d));
    float sum = 0.f;
#pragma unroll
    for (int nt = 0; nt < 5; ++nt) {
      float e = __expf(p[nt][r] - mx);
      p[nt][r] = e;
      sum += e;
    }
#pragma unroll
    for (int d = 1; d < 16; d <<= 1) sum += __shfl_xor(sum, d);
    float inv = 1.f / sum;
#pragma unroll
    for (int nt = 0; nt < 5; ++nt) p[nt][r] *= inv;
  }

#pragma unroll
  for (int r = 0; r < 4; ++r)
#pragma unroll
    for (int nt = 0; nt < 5; ++nt)
      Psm[wid][lq * 4 + r][nt * 16 + lr] = f2h(p[nt][r]);

  f32x4 ov[10];
#pragma unroll
  for (int n2 = 0; n2 < 10; ++n2) ov[n2] = (f32x4){0.f, 0.f, 0.f, 0.f};
#pragma unroll
  for (int k2 = 0; k2 < 3; ++k2) {
    f16x8 pf = *(const f16x8*)&Psm[wid][lr][k2 * 32 + koff];
#pragma unroll
    for (int n2 = 0; n2 < 10; ++n2) {
      f16x8 vf = *(const f16x8*)&VT[n2 * 16 + lr][k2 * 32 + koff];
      ov[n2] = mfma16(pf, vf, ov[n2]);
    }
  }

  const size_t obase =
      ((size_t)b * 4096 + (size_t)qt * 64 + wid * 16 + lq * 4) * 1280 +
      (size_t)h * 160;
#pragma unroll
  for (int r = 0; r < 4; ++r)
#pragma unroll
    for (int n2 = 0; n2 < 10; ++n2)
      Oa[obase + (size_t)r * 1280 + n2 * 16 + lr] = f2h(ov[n2][r]);
}

// ---------------- host orchestration ----------------------------------------
extern "C" void kernel_launch(void* const* d_in, const int* in_sizes, int n_in,
                              void* d_out, int out_size, void* d_ws,
                              size_t ws_size, hipStream_t stream) {
  (void)in_sizes; (void)n_in; (void)out_size; (void)ws_size;
  const float* hs  = (const float*)d_in[0];
  const float* enc = (const float*)d_in[1];
  const float* Wq  = (const float*)d_in[2];
  const float* Wk  = (const float*)d_in[3];
  const float* Wv  = (const float*)d_in[4];
  const float* Wo  = (const float*)d_in[5];
  const float* bo  = (const float*)d_in[6];
  float* out = (float*)d_out;

  const int B = 16, S = 4096, SKV = 77, HID = 1280, CDIM = 768;
  const int MQ = B * S;
  const int MKV = B * SKV;

  char* ws = (char*)d_ws;
  size_t off = 0;
  auto alloc = [&](size_t bytes) -> char* {
    char* p = ws + off;
    off += (bytes + 255) & ~(size_t)255;
    return p;
  };
  u16* hs_h  = (u16*)alloc((size_t)MQ * HID * 2);
  u16* q_h   = (u16*)alloc((size_t)MQ * HID * 2);
  u16* enc_h = (u16*)alloc((size_t)MKV * CDIM * 2);
  u16* wq_h  = (u16*)alloc((size_t)HID * HID * 2);
  u16* wk_h  = (u16*)alloc((size_t)HID * CDIM * 2);
  u16* wv_h  = (u16*)alloc((size_t)HID * CDIM * 2);
  u16* wo_h  = (u16*)alloc((size_t)HID * HID * 2);
  u16* k_h   = (u16*)alloc((size_t)MKV * HID * 2);
  u16* v_h   = (u16*)alloc((size_t)MKV * HID * 2);
  u16* attn_h = hs_h;  // hs_h dead after Q projection

  auto cvt = [&](const float* src, u16* dst, long n) {
    long n8 = n / 8;
    int blocks = (int)((n8 + 255) / 256);
    if (blocks > 2048) blocks = 2048;
    cvt_f32_f16<<<blocks, 256, 0, stream>>>(src, dst, n8);
  };
  cvt(hs,  hs_h,  (long)MQ * HID);
  cvt(enc, enc_h, (long)MKV * CDIM);
  cvt(Wq,  wq_h,  (long)HID * HID);
  cvt(Wk,  wk_h,  (long)HID * CDIM);
  cvt(Wv,  wv_h,  (long)HID * CDIM);
  cvt(Wo,  wo_h,  (long)HID * HID);

  // K/V projections (small, tail): 128^2 kernel
  gemm_bt<1, 0, 1><<<dim3(10, 10), 256, 0, stream>>>(enc_h, wk_h, k_h, nullptr, MKV, HID, CDIM);
  gemm_bt<1, 0, 1><<<dim3(10, 10), 256, 0, stream>>>(enc_h, wv_h, v_h, nullptr, MKV, HID, CDIM);

  // Q projection: 256^2 pipelined kernel. grid = (M/256)*(N/256)
  const int grid_big = (MQ / 256) * (HID / 256);
  gemm_bt8<1, 0><<<dim3(grid_big), dim3(512), 131072, stream>>>(
      hs_h, wq_h, q_h, nullptr, MQ, HID, HID);

  const float scale = 1.0f / sqrtf(160.0f);
  attn_fused<<<dim3(64, 8, 16), 256, 0, stream>>>(q_h, k_h, v_h, attn_h, scale);

  // output projection (+bias, f32 out)
  gemm_bt8<0, 1><<<dim3(grid_big), dim3(512), 131072, stream>>>(
      attn_h, wo_h, out, bo, MQ, HID, HID);
}

// Round 8
// 827.055 us; speedup vs baseline: 1.0250x; 1.0101x over previous
//
#include <hip/hip_runtime.h>
#include <stdint.h>
#include <cmath>

typedef unsigned short u16;
typedef _Float16 f16;
typedef f16   f16x8 __attribute__((ext_vector_type(8)));
typedef float f32x4 __attribute__((ext_vector_type(4)));
typedef u16   u16x8 __attribute__((ext_vector_type(8)));

#define GLD16(gsrc, ldst)                                                      \
  __builtin_amdgcn_global_load_lds(                                            \
      (__attribute__((address_space(1))) void*)(gsrc),                         \
      (__attribute__((address_space(3))) void*)(ldst), 16, 0, 0)

__device__ __forceinline__ u16 f2h(float x) {
  f16 h = (f16)x;
  return __builtin_bit_cast(u16, h);
}

__device__ __forceinline__ f32x4 mfma16(f16x8 a, f16x8 b, f32x4 c) {
  return __builtin_amdgcn_mfma_f32_16x16x32_f16(a, b, c, 0, 0, 0);
}

// ---------------- f32 -> f16 convert (vectorized, 8 elems/thread/iter) ------
__global__ void cvt_f32_f16(const float* __restrict__ in, u16* __restrict__ out,
                            long n8) {
  long i = (long)blockIdx.x * 256 + threadIdx.x;
  const long stride = (long)gridDim.x * 256;
  for (; i < n8; i += stride) {
    const float4* p = (const float4*)in + 2 * i;
    float4 a = p[0], b = p[1];
    u16x8 o;
    o[0] = f2h(a.x); o[1] = f2h(a.y); o[2] = f2h(a.z); o[3] = f2h(a.w);
    o[4] = f2h(b.x); o[5] = f2h(b.y); o[6] = f2h(b.z); o[7] = f2h(b.w);
    *((u16x8*)out + i) = o;
  }
}

// ================= 256x256 pipelined GEMM  C[M,N] = A[M,K]*B[N,K]^T =========
// (unchanged from r7: 268 us, MfmaUtil 34%, 0 bank conflicts)
__device__ __forceinline__ int swz_addr(int r, int ckbyte) {
  int line = r >> 1;
  return line * 128 + ((((r & 1) << 6) | ckbyte) ^ ((line & 7) << 4));
}

template <int OUT_F16, int HAS_BIAS>
__global__ __launch_bounds__(512, 2) void gemm_bt8(const u16* __restrict__ A,
                                                   const u16* __restrict__ B,
                                                   void* __restrict__ Cp,
                                                   const float* __restrict__ bias,
                                                   int M, int N, int K) {
  extern __shared__ char smem[];  // 131072 bytes: buf q at q*32768; A then B
  const int tid = threadIdx.x;
  const int lane = tid & 63, wid = tid >> 6;
  const int wm = wid >> 2, wn = wid & 3;  // 2 x 4 waves
  const int lq = lane >> 4, lr = lane & 15;

  // ---- bijective XCD swizzle (m204) ----
  int nwg = gridDim.x;
  int orig = blockIdx.x;
  int q8 = nwg >> 3, r8 = nwg & 7;
  int xcd = orig & 7, idx = orig >> 3;
  int wg = (xcd < r8 ? xcd * (q8 + 1) : r8 * (q8 + 1) + (xcd - r8) * q8) + idx;
  const int gn = N >> 8;
  const int mb = wg / gn, nb = wg % gn;
  const int m0 = mb * 256, n0 = nb * 256;

  const int NT = K >> 5;  // K-tiles of 32

  // ---- per-thread staging source decode (inverse swizzle on global src) ----
  int offs[2];
  offs[0] = wid * 1024 + lane * 16;
  offs[1] = offs[0] + 8192;
  const u16* srcA[2];
  const u16* srcB[2];
#pragma unroll
  for (int is = 0; is < 2; ++is) {
    int off = offs[is];
    int line = off >> 7;
    int j2 = (off & 127) ^ ((line & 7) << 4);
    int r = 2 * line + (j2 >> 6), ck = j2 & 63;
    srcA[is] = A + (size_t)(m0 + r) * K + (ck >> 1);
    srcB[is] = B + (size_t)(n0 + r) * K + (ck >> 1);
  }

#define GLDA(t)                                                               \
  do {                                                                        \
    char* db = smem + ((t) & 3) * 32768 + wid * 1024;                         \
    GLD16(srcA[0] + (size_t)(t) * 32, db);                                    \
    GLD16(srcA[1] + (size_t)(t) * 32, db + 8192);                             \
  } while (0)
#define GLDB(t)                                                               \
  do {                                                                        \
    char* db = smem + ((t) & 3) * 32768 + 16384 + wid * 1024;                 \
    GLD16(srcB[0] + (size_t)(t) * 32, db);                                    \
    GLD16(srcB[1] + (size_t)(t) * 32, db + 8192);                             \
  } while (0)

  // ---- fragment LDS addresses (swizzled) ----
  int addrA[8], addrB[4];
#pragma unroll
  for (int m = 0; m < 8; ++m)
    addrA[m] = swz_addr(wm * 128 + m * 16 + lr, lq * 16);
#pragma unroll
  for (int n = 0; n < 4; ++n)
    addrB[n] = 16384 + swz_addr(wn * 64 + n * 16 + lr, lq * 16);

  f32x4 acc[8][4] = {};

  // ---- prologue: prefetch K-tiles 0,1,2 ----
#pragma unroll
  for (int t = 0; t < 3; ++t) {
    GLDA(t);
    GLDB(t);
  }
  asm volatile("s_waitcnt vmcnt(8)" ::: "memory");
  __builtin_amdgcn_s_barrier();

  for (int c = 0; c < NT; ++c) {
    const char* bb = smem + (c & 3) * 32768;
    const int pf = c + 3;
    // ================= phase A: quadrant m0..3 =============================
    f16x8 bfr[4], afr[4];
#pragma unroll
    for (int n = 0; n < 4; ++n) bfr[n] = *(const f16x8*)(bb + addrB[n]);
#pragma unroll
    for (int m = 0; m < 4; ++m) afr[m] = *(const f16x8*)(bb + addrA[m]);
    if (pf < NT) GLDA(pf);
    __builtin_amdgcn_s_barrier();
    asm volatile("s_waitcnt lgkmcnt(0)" ::: "memory");
    __builtin_amdgcn_s_setprio(1);
#pragma unroll
    for (int m = 0; m < 4; ++m)
#pragma unroll
      for (int n = 0; n < 4; ++n)
        acc[m][n] = mfma16(afr[m], bfr[n], acc[m][n]);
    __builtin_amdgcn_s_setprio(0);
    __builtin_amdgcn_s_barrier();
    // ================= phase B: quadrant m4..7 =============================
    f16x8 afr2[4];
#pragma unroll
    for (int m = 0; m < 4; ++m) afr2[m] = *(const f16x8*)(bb + addrA[4 + m]);
    if (pf < NT) GLDB(pf);
    if (c + 3 < NT)
      asm volatile("s_waitcnt vmcnt(8)" ::: "memory");
    else if (c + 2 < NT)
      asm volatile("s_waitcnt vmcnt(4)" ::: "memory");
    else if (c + 1 < NT)
      asm volatile("s_waitcnt vmcnt(0)" ::: "memory");
    __builtin_amdgcn_s_barrier();
    asm volatile("s_waitcnt lgkmcnt(0)" ::: "memory");
    __builtin_amdgcn_s_setprio(1);
#pragma unroll
    for (int m = 0; m < 4; ++m)
#pragma unroll
      for (int n = 0; n < 4; ++n)
        acc[4 + m][n] = mfma16(afr2[m], bfr[n], acc[4 + m][n]);
    __builtin_amdgcn_s_setprio(0);
    __builtin_amdgcn_s_barrier();
  }
#undef GLDA
#undef GLDB

  // ---- epilogue ----
  const int mbase = m0 + wm * 128, nbase = n0 + wn * 64;
  float bv[4];
#pragma unroll
  for (int n = 0; n < 4; ++n)
    bv[n] = HAS_BIAS ? bias[nbase + n * 16 + lr] : 0.0f;
#pragma unroll
  for (int m = 0; m < 8; ++m) {
#pragma unroll
    for (int r = 0; r < 4; ++r) {
      int grow = mbase + m * 16 + lq * 4 + r;
#pragma unroll
      for (int n = 0; n < 4; ++n) {
        int gcol = nbase + n * 16 + lr;
        float v = acc[m][n][r] + bv[n];
        if (OUT_F16)
          ((u16*)Cp)[(size_t)grow * N + gcol] = f2h(v);
        else
          ((float*)Cp)[(size_t)grow * N + gcol] = v;
      }
    }
  }
}

// ---------------- small GEMM (K/V projections, M=1232 w/ tail) --------------
template <int OUT_F16, int HAS_BIAS, int MTAIL>
__global__ __launch_bounds__(256) void gemm_bt(const u16* __restrict__ A,
                                               const u16* __restrict__ B,
                                               void* __restrict__ Cp,
                                               const float* __restrict__ bias,
                                               int M, int N, int K) {
  constexpr int BK = 64;
  __shared__ u16 Asm[128 * BK];
  __shared__ u16 Bsm[128 * BK];
  const int tid = threadIdx.x;
  const int lane = tid & 63, wid = tid >> 6;
  const int wm = wid >> 1, wn = wid & 1;
  const int m0 = blockIdx.y * 128, n0 = blockIdx.x * 128;
  const int lq = lane >> 4, lr = lane & 15;
  const int koff = lq << 3;

  f32x4 acc[4][4] = {};

  for (int k0 = 0; k0 < K; k0 += BK) {
#pragma unroll
    for (int j = 0; j < 4; ++j) {
      int off = (wid * 4 + j) * 1024 + lane * 16;
      int r = off >> 7;
      int c = (off & 127) >> 1;
      int gr = m0 + r;
      if (MTAIL) gr = gr < M ? gr : M - 1;
      GLD16(A + (size_t)gr * K + k0 + c, (char*)Asm + (wid * 4 + j) * 1024);
    }
#pragma unroll
    for (int j = 0; j < 4; ++j) {
      int off = (wid * 4 + j) * 1024 + lane * 16;
      int r = off >> 7;
      int c = (off & 127) >> 1;
      GLD16(B + (size_t)(n0 + r) * K + k0 + c, (char*)Bsm + (wid * 4 + j) * 1024);
    }
    __syncthreads();
#pragma unroll
    for (int ks = 0; ks < 2; ++ks) {
      f16x8 af[4], bfr[4];
#pragma unroll
      for (int m = 0; m < 4; ++m)
        af[m] = *(const f16x8*)(Asm + (wm * 64 + m * 16 + lr) * BK + ks * 32 + koff);
#pragma unroll
      for (int n = 0; n < 4; ++n)
        bfr[n] = *(const f16x8*)(Bsm + (wn * 64 + n * 16 + lr) * BK + ks * 32 + koff);
#pragma unroll
      for (int m = 0; m < 4; ++m)
#pragma unroll
        for (int n = 0; n < 4; ++n)
          acc[m][n] = mfma16(af[m], bfr[n], acc[m][n]);
    }
    __syncthreads();
  }

#pragma unroll
  for (int m = 0; m < 4; ++m) {
#pragma unroll
    for (int r = 0; r < 4; ++r) {
      int grow = m0 + wm * 64 + m * 16 + lq * 4 + r;
      if (MTAIL && grow >= M) continue;
#pragma unroll
      for (int n = 0; n < 4; ++n) {
        int gcol = n0 + wn * 64 + n * 16 + lr;
        float v = acc[m][n][r];
        if (HAS_BIAS) v += bias[gcol];
        if (OUT_F16)
          ((u16*)Cp)[(size_t)grow * N + gcol] = f2h(v);
        else
          ((float*)Cp)[(size_t)grow * N + gcol] = v;
      }
    }
  }
}

// ---------------- fused attention (4 q-tiles per block) ---------------------
// grid (16 q-groups, 8 heads, 16 batch); block 256 = 4 waves * 16 q-rows.
// K/V staged + LDS zero-fill ONCE per block, reused across 4 q-tiles.
__global__ __launch_bounds__(256) void attn_fused(const u16* __restrict__ Q,
                                                  const u16* __restrict__ Kp,
                                                  const u16* __restrict__ Vp,
                                                  u16* __restrict__ Oa,
                                                  float scale) {
  __shared__ u16 Ksm[80][168];
  __shared__ u16 VT[160][104];
  __shared__ u16 Psm[4][16][96];
  const int tid = threadIdx.x, lane = tid & 63, wid = tid >> 6;
  const int lq = lane >> 4, lr = lane & 15, koff = lq << 3;
  const int qg = blockIdx.x, h = blockIdx.y, b = blockIdx.z;

  {  // zero-fill LDS once (pads + masked tail rows stay zero for all tiles)
    u16x8 z = {0, 0, 0, 0, 0, 0, 0, 0};
    for (int i = tid; i < 80 * 168 / 8; i += 256) ((u16x8*)&Ksm[0][0])[i] = z;
    for (int i = tid; i < 160 * 104 / 8; i += 256) ((u16x8*)&VT[0][0])[i] = z;
    for (int i = tid; i < 4 * 16 * 96 / 8; i += 256) ((u16x8*)&Psm[0][0][0])[i] = z;
  }
  __syncthreads();

  const size_t kvbase = ((size_t)b * 77) * 1280 + (size_t)h * 160;
  for (int i = tid; i < 77 * 20; i += 256) {  // K rows, contiguous
    int r = i / 20, c8 = (i % 20) * 8;
    *(u16x8*)&Ksm[r][c8] = *(const u16x8*)(Kp + kvbase + (size_t)r * 1280 + c8);
  }
  for (int i = tid; i < 77 * 20; i += 256) {  // V transposed into [dim][key]
    int r = i / 20, c8 = (i % 20) * 8;
    u16x8 v = *(const u16x8*)(Vp + kvbase + (size_t)r * 1280 + c8);
#pragma unroll
    for (int j = 0; j < 8; ++j) VT[c8 + j][r] = v[j];
  }
  __syncthreads();

  for (int it = 0; it < 4; ++it) {
    const int qt = qg * 4 + it;

    // Q fragments (global, per wave 16 q-rows)
    f16x8 qf[5];
    const int qrow = qt * 64 + wid * 16 + lr;
    const size_t qbase = ((size_t)b * 4096 + qrow) * 1280 + (size_t)h * 160;
#pragma unroll
    for (int ks = 0; ks < 5; ++ks)
      qf[ks] = *(const f16x8*)(Q + qbase + ks * 32 + koff);

    // scores: 16x80 per wave = Q(16x160) * K^T
    f32x4 sc[5];
#pragma unroll
    for (int nt = 0; nt < 5; ++nt) {
      sc[nt] = (f32x4){0.f, 0.f, 0.f, 0.f};
#pragma unroll
      for (int ks = 0; ks < 5; ++ks) {
        f16x8 kf = *(const f16x8*)&Ksm[nt * 16 + lr][ks * 32 + koff];
        sc[nt] = mfma16(qf[ks], kf, sc[nt]);
      }
    }

    // softmax over keys
    float p[5][4];
#pragma unroll
    for (int r = 0; r < 4; ++r) {
      float mx = -1e30f;
#pragma unroll
      for (int nt = 0; nt < 5; ++nt) {
        float v = sc[nt][r] * scale;
        if (nt * 16 + lr >= 77) v = -1e30f;
        p[nt][r] = v;
        mx = fmaxf(mx, v);
      }
#pragma unroll
      for (int d = 1; d < 16; d <<= 1) mx = fmaxf(mx, __shfl_xor(mx, d));
      float sum = 0.f;
#pragma unroll
      for (int nt = 0; nt < 5; ++nt) {
        float e = __expf(p[nt][r] - mx);
        p[nt][r] = e;
        sum += e;
      }
#pragma unroll
      for (int d = 1; d < 16; d <<= 1) sum += __shfl_xor(sum, d);
      float inv = 1.f / sum;
#pragma unroll
      for (int nt = 0; nt < 5; ++nt) p[nt][r] *= inv;
    }

    // P -> per-wave LDS (re-layout C-frag -> A-frag); per-wave, no x-wave hazard
#pragma unroll
    for (int r = 0; r < 4; ++r)
#pragma unroll
      for (int nt = 0; nt < 5; ++nt)
        Psm[wid][lq * 4 + r][nt * 16 + lr] = f2h(p[nt][r]);

    // PV: out(16x160) = P(16x96) * V(96x160)
    f32x4 ov[10];
#pragma unroll
    for (int n2 = 0; n2 < 10; ++n2) ov[n2] = (f32x4){0.f, 0.f, 0.f, 0.f};
#pragma unroll
    for (int k2 = 0; k2 < 3; ++k2) {
      f16x8 pf = *(const f16x8*)&Psm[wid][lr][k2 * 32 + koff];
#pragma unroll
      for (int n2 = 0; n2 < 10; ++n2) {
        f16x8 vf = *(const f16x8*)&VT[n2 * 16 + lr][k2 * 32 + koff];
        ov[n2] = mfma16(pf, vf, ov[n2]);
      }
    }

    const size_t obase =
        ((size_t)b * 4096 + (size_t)qt * 64 + wid * 16 + lq * 4) * 1280 +
        (size_t)h * 160;
#pragma unroll
    for (int r = 0; r < 4; ++r)
#pragma unroll
      for (int n2 = 0; n2 < 10; ++n2)
        Oa[obase + (size_t)r * 1280 + n2 * 16 + lr] = f2h(ov[n2][r]);
  }
}

// ---------------- host orchestration ----------------------------------------
extern "C" void kernel_launch(void* const* d_in, const int* in_sizes, int n_in,
                              void* d_out, int out_size, void* d_ws,
                              size_t ws_size, hipStream_t stream) {
  (void)in_sizes; (void)n_in; (void)out_size; (void)ws_size;
  const float* hs  = (const float*)d_in[0];
  const float* enc = (const float*)d_in[1];
  const float* Wq  = (const float*)d_in[2];
  const float* Wk  = (const float*)d_in[3];
  const float* Wv  = (const float*)d_in[4];
  const float* Wo  = (const float*)d_in[5];
  const float* bo  = (const float*)d_in[6];
  float* out = (float*)d_out;

  const int B = 16, S = 4096, SKV = 77, HID = 1280, CDIM = 768;
  const int MQ = B * S;
  const int MKV = B * SKV;

  char* ws = (char*)d_ws;
  size_t off = 0;
  auto alloc = [&](size_t bytes) -> char* {
    char* p = ws + off;
    off += (bytes + 255) & ~(size_t)255;
    return p;
  };
  u16* hs_h  = (u16*)alloc((size_t)MQ * HID * 2);
  u16* q_h   = (u16*)alloc((size_t)MQ * HID * 2);
  u16* enc_h = (u16*)alloc((size_t)MKV * CDIM * 2);
  u16* wq_h  = (u16*)alloc((size_t)HID * HID * 2);
  u16* wk_h  = (u16*)alloc((size_t)HID * CDIM * 2);
  u16* wv_h  = (u16*)alloc((size_t)HID * CDIM * 2);
  u16* wo_h  = (u16*)alloc((size_t)HID * HID * 2);
  u16* k_h   = (u16*)alloc((size_t)MKV * HID * 2);
  u16* v_h   = (u16*)alloc((size_t)MKV * HID * 2);
  u16* attn_h = hs_h;  // hs_h dead after Q projection

  auto cvt = [&](const float* src, u16* dst, long n) {
    long n8 = n / 8;
    int blocks = (int)((n8 + 255) / 256);
    if (blocks > 2048) blocks = 2048;
    cvt_f32_f16<<<blocks, 256, 0, stream>>>(src, dst, n8);
  };
  cvt(hs,  hs_h,  (long)MQ * HID);
  cvt(enc, enc_h, (long)MKV * CDIM);
  cvt(Wq,  wq_h,  (long)HID * HID);
  cvt(Wk,  wk_h,  (long)HID * CDIM);
  cvt(Wv,  wv_h,  (long)HID * CDIM);
  cvt(Wo,  wo_h,  (long)HID * HID);

  // K/V projections (small, tail): 128^2 kernel
  gemm_bt<1, 0, 1><<<dim3(10, 10), 256, 0, stream>>>(enc_h, wk_h, k_h, nullptr, MKV, HID, CDIM);
  gemm_bt<1, 0, 1><<<dim3(10, 10), 256, 0, stream>>>(enc_h, wv_h, v_h, nullptr, MKV, HID, CDIM);

  // Q projection: 256^2 pipelined kernel. grid = (M/256)*(N/256)
  const int grid_big = (MQ / 256) * (HID / 256);
  gemm_bt8<1, 0><<<dim3(grid_big), dim3(512), 131072, stream>>>(
      hs_h, wq_h, q_h, nullptr, MQ, HID, HID);

  const float scale = 1.0f / sqrtf(160.0f);
  attn_fused<<<dim3(16, 8, 16), 256, 0, stream>>>(q_h, k_h, v_h, attn_h, scale);

  // output projection (+bias, f32 out)
  gemm_bt8<0, 1><<<dim3(grid_big), dim3(512), 131072, stream>>>(
      attn_h, wo_h, out, bo, MQ, HID, HID);
}

// Round 9
// 812.089 us; speedup vs baseline: 1.0438x; 1.0184x over previous
//
#include <hip/hip_runtime.h>
#include <stdint.h>
#include <cmath>

typedef unsigned short u16;
typedef _Float16 f16;
typedef f16   f16x8 __attribute__((ext_vector_type(8)));
typedef float f32x4 __attribute__((ext_vector_type(4)));
typedef u16   u16x8 __attribute__((ext_vector_type(8)));

#define GLD16(gsrc, ldst)                                                      \
  __builtin_amdgcn_global_load_lds(                                            \
      (__attribute__((address_space(1))) void*)(gsrc),                         \
      (__attribute__((address_space(3))) void*)(ldst), 16, 0, 0)

__device__ __forceinline__ u16 f2h(float x) {
  f16 h = (f16)x;
  return __builtin_bit_cast(u16, h);
}

__device__ __forceinline__ f32x4 mfma16(f16x8 a, f16x8 b, f32x4 c) {
  return __builtin_amdgcn_mfma_f32_16x16x32_f16(a, b, c, 0, 0, 0);
}

// ---------------- f32 -> f16 convert (vectorized, 8 elems/thread/iter) ------
__global__ void cvt_f32_f16(const float* __restrict__ in, u16* __restrict__ out,
                            long n8) {
  long i = (long)blockIdx.x * 256 + threadIdx.x;
  const long stride = (long)gridDim.x * 256;
  for (; i < n8; i += stride) {
    const float4* p = (const float4*)in + 2 * i;
    float4 a = p[0], b = p[1];
    u16x8 o;
    o[0] = f2h(a.x); o[1] = f2h(a.y); o[2] = f2h(a.z); o[3] = f2h(a.w);
    o[4] = f2h(b.x); o[5] = f2h(b.y); o[6] = f2h(b.z); o[7] = f2h(b.w);
    *((u16x8*)out + i) = o;
  }
}

// ===== 256x256 quadrant-rotation 8-phase GEMM  C[M,N]=A[M,K]*B[N,K]^T =======
// m201-template port. 512 thr = 8 waves (2M x 4N); BK=64; 2 LDS buffers
// (2 x 64KB). Per K-tile: 4 phases, each = one 128x128 block-quadrant
// (wave sub-tile 64x32, 16 MFMA) consuming ONE A-half + ONE B-half.
// Stage 1 half-tile of t+1 per phase; counted vmcnt(4) at P0/P1/P3 keeps
// 4-8 loads in flight, never drains to 0 (tails: vmcnt(2)/vmcnt(0)).
// LDS: [256][64] f16 rows (128B), byte-swizzle kb ^= ((row&7)<<4):
// frag reads 2-way max (free); staging sources pre-inverse-swizzled.
// Requires M%256==0, N%256==0, K%64==0, K/64>=2.
template <int OUT_F16, int HAS_BIAS>
__global__ __launch_bounds__(512, 2) void gemm_8ph(const u16* __restrict__ A,
                                                   const u16* __restrict__ B,
                                                   void* __restrict__ Cp,
                                                   const float* __restrict__ bias,
                                                   int M, int N, int K) {
  extern __shared__ char smem[];  // 131072: buf b at b*65536; A @0, B @32768
  const int tid = threadIdx.x;
  const int lane = tid & 63, wid = tid >> 6;
  const int wm = wid >> 2, wn = wid & 3;  // 2M x 4N waves
  const int lq = lane >> 4, lr = lane & 15;

  // ---- bijective XCD swizzle (m204) ----
  int nwg = gridDim.x;
  int orig = blockIdx.x;
  int q8 = nwg >> 3, r8 = nwg & 7;
  int xcd = orig & 7, idx = orig >> 3;
  int wg = (xcd < r8 ? xcd * (q8 + 1) : r8 * (q8 + 1) + (xcd - r8) * q8) + idx;
  const int gn = N >> 8;
  const int mb = wg / gn, nb = wg % gn;
  const int m0 = mb * 256, n0 = nb * 256;

  const int NT = K >> 6;  // K-tiles of 64

  // ---- staging source decode (pre-inverse-swizzled global addresses) ----
  // thread covers rows r0=tid>>3 (+64 for l=1, +128 for half=1), 16B at kb0.
  const int r0 = tid >> 3;
  const int kb0 = (((tid & 7) ^ ((tid >> 3) & 7)) << 4);
  const u16* pA = A + (size_t)(m0 + r0) * K + (kb0 >> 1);
  const u16* pB = B + (size_t)(n0 + r0) * K + (kb0 >> 1);

#define STAGE(MAT, HALF, TT)                                                  \
  do {                                                                        \
    char* db_ = smem + ((TT) & 1) * 65536 + (MAT) * 32768 +                   \
                (HALF) * 16384 + wid * 1024;                                  \
    const u16* s_ = (MAT ? pB : pA) + (size_t)((HALF) * 128) * K +            \
                    (size_t)(TT) * 64;                                        \
    GLD16(s_, db_);                                                           \
    GLD16(s_ + (size_t)64 * K, db_ + 8192);                                   \
  } while (0)

  // ---- fragment LDS address constants ----
  // addrA(qm,m2,ks) = ABASE + qm*16384 + m2*2048 + kx[ks]
  int kx[2];
#pragma unroll
  for (int ks = 0; ks < 2; ++ks)
    kx[ks] = ((ks * 64 + lq * 16) ^ ((lr & 7) << 4));
  const int ABASE = wm * 8192 + lr * 128;
  const int BBASE = 32768 + wn * 4096 + lr * 128;

#define READA(FA, QM)                                                         \
  _Pragma("unroll") for (int m2 = 0; m2 < 4; ++m2)                            \
  _Pragma("unroll") for (int ks = 0; ks < 2; ++ks)                            \
    FA[m2][ks] = *(const f16x8*)(rb + ABASE + (QM) * 16384 + m2 * 2048 + kx[ks]);
#define READB(FB, QN)                                                         \
  _Pragma("unroll") for (int n2 = 0; n2 < 2; ++n2)                            \
  _Pragma("unroll") for (int ks = 0; ks < 2; ++ks)                            \
    FB[n2][ks] = *(const f16x8*)(rb + BBASE + (QN) * 16384 + n2 * 2048 + kx[ks]);

#define CLUSTER(QM, QN, FA, FB)                                               \
  __builtin_amdgcn_s_setprio(1);                                              \
  _Pragma("unroll") for (int m2 = 0; m2 < 4; ++m2)                            \
  _Pragma("unroll") for (int n2 = 0; n2 < 2; ++n2)                            \
  _Pragma("unroll") for (int ks = 0; ks < 2; ++ks)                            \
      acc[QM][QN][m2][n2] =                                                   \
          mfma16(FA[m2][ks], FB[n2][ks], acc[QM][QN][m2][n2]);                \
  __builtin_amdgcn_s_setprio(0);

  f32x4 acc[2][2][4][2] = {};

  // ---- prologue: stage tile 0 fully, drain, barrier ----
  STAGE(0, 0, 0);
  STAGE(1, 0, 0);
  STAGE(0, 1, 0);
  STAGE(1, 1, 0);
  asm volatile("s_waitcnt vmcnt(0)" ::: "memory");
  __builtin_amdgcn_s_barrier();

  for (int t = 0; t < NT; ++t) {
    const char* rb = smem + (t & 1) * 65536;
    f16x8 fa0[4][2], fa1[4][2], fb0[2][2], fb1[2][2];
    // ===== P0: quadrant (qm0,qn0) — uses A-h0, B-h0 =====
    READA(fa0, 0);
    READB(fb0, 0);
    if (t + 1 < NT) {
      STAGE(0, 0, t + 1);  // A-h0 of t+1
      asm volatile("s_waitcnt vmcnt(4)" ::: "memory");  // A1(t) landed
    } else {
      asm volatile("s_waitcnt vmcnt(2)" ::: "memory");
    }
    __builtin_amdgcn_s_barrier();
    asm volatile("s_waitcnt lgkmcnt(0)" ::: "memory");
    CLUSTER(0, 0, fa0, fb0);
    __builtin_amdgcn_s_barrier();
    // ===== P1: quadrant (qm1,qn0) — A-h1 (fresh), B-h0 (held) =====
    READA(fa1, 1);
    if (t + 1 < NT) {
      STAGE(1, 0, t + 1);  // B-h0 of t+1
      asm volatile("s_waitcnt vmcnt(4)" ::: "memory");  // B1(t) landed
    } else {
      asm volatile("s_waitcnt vmcnt(0)" ::: "memory");
    }
    __builtin_amdgcn_s_barrier();
    asm volatile("s_waitcnt lgkmcnt(0)" ::: "memory");
    CLUSTER(1, 0, fa1, fb0);
    __builtin_amdgcn_s_barrier();
    // ===== P2: quadrant (qm1,qn1) — A-h1 (held), B-h1 (fresh) =====
    READB(fb1, 1);
    if (t + 1 < NT) STAGE(0, 1, t + 1);  // A-h1 of t+1
    __builtin_amdgcn_s_barrier();
    asm volatile("s_waitcnt lgkmcnt(0)" ::: "memory");
    CLUSTER(1, 1, fa1, fb1);
    __builtin_amdgcn_s_barrier();
    // ===== P3: quadrant (qm0,qn1) — A-h0 (re-read), B-h1 (held) =====
    READA(fa0, 0);
    if (t + 1 < NT) {
      STAGE(1, 1, t + 1);  // B-h1 of t+1
      asm volatile("s_waitcnt vmcnt(4)" ::: "memory");  // A0,B0(t+1) landed
    }
    __builtin_amdgcn_s_barrier();
    asm volatile("s_waitcnt lgkmcnt(0)" ::: "memory");
    CLUSTER(0, 1, fa0, fb1);
    __builtin_amdgcn_s_barrier();
  }
#undef STAGE
#undef READA
#undef READB
#undef CLUSTER

  // ---- epilogue: C-row = m0+qm*128+wm*64+m2*16+lq*4+r;
  //                C-col = n0+qn*128+wn*32+n2*16+lr
  float bv[2][2];
#pragma unroll
  for (int qn = 0; qn < 2; ++qn)
#pragma unroll
    for (int n2 = 0; n2 < 2; ++n2)
      bv[qn][n2] =
          HAS_BIAS ? bias[n0 + qn * 128 + wn * 32 + n2 * 16 + lr] : 0.0f;
#pragma unroll
  for (int qm = 0; qm < 2; ++qm) {
#pragma unroll
    for (int m2 = 0; m2 < 4; ++m2) {
#pragma unroll
      for (int r = 0; r < 4; ++r) {
        int grow = m0 + qm * 128 + wm * 64 + m2 * 16 + lq * 4 + r;
#pragma unroll
        for (int qn = 0; qn < 2; ++qn) {
#pragma unroll
          for (int n2 = 0; n2 < 2; ++n2) {
            int gcol = n0 + qn * 128 + wn * 32 + n2 * 16 + lr;
            float v = acc[qm][qn][m2][n2][r] + bv[qn][n2];
            if (OUT_F16)
              ((u16*)Cp)[(size_t)grow * N + gcol] = f2h(v);
            else
              ((float*)Cp)[(size_t)grow * N + gcol] = v;
          }
        }
      }
    }
  }
}

// ---------------- small GEMM (K/V projections, M=1232 w/ tail) --------------
template <int OUT_F16, int HAS_BIAS, int MTAIL>
__global__ __launch_bounds__(256) void gemm_bt(const u16* __restrict__ A,
                                               const u16* __restrict__ B,
                                               void* __restrict__ Cp,
                                               const float* __restrict__ bias,
                                               int M, int N, int K) {
  constexpr int BK = 64;
  __shared__ u16 Asm[128 * BK];
  __shared__ u16 Bsm[128 * BK];
  const int tid = threadIdx.x;
  const int lane = tid & 63, wid = tid >> 6;
  const int wm = wid >> 1, wn = wid & 1;
  const int m0 = blockIdx.y * 128, n0 = blockIdx.x * 128;
  const int lq = lane >> 4, lr = lane & 15;
  const int koff = lq << 3;

  f32x4 acc[4][4] = {};

  for (int k0 = 0; k0 < K; k0 += BK) {
#pragma unroll
    for (int j = 0; j < 4; ++j) {
      int off = (wid * 4 + j) * 1024 + lane * 16;
      int r = off >> 7;
      int c = (off & 127) >> 1;
      int gr = m0 + r;
      if (MTAIL) gr = gr < M ? gr : M - 1;
      GLD16(A + (size_t)gr * K + k0 + c, (char*)Asm + (wid * 4 + j) * 1024);
    }
#pragma unroll
    for (int j = 0; j < 4; ++j) {
      int off = (wid * 4 + j) * 1024 + lane * 16;
      int r = off >> 7;
      int c = (off & 127) >> 1;
      GLD16(B + (size_t)(n0 + r) * K + k0 + c, (char*)Bsm + (wid * 4 + j) * 1024);
    }
    __syncthreads();
#pragma unroll
    for (int ks = 0; ks < 2; ++ks) {
      f16x8 af[4], bfr[4];
#pragma unroll
      for (int m = 0; m < 4; ++m)
        af[m] = *(const f16x8*)(Asm + (wm * 64 + m * 16 + lr) * BK + ks * 32 + koff);
#pragma unroll
      for (int n = 0; n < 4; ++n)
        bfr[n] = *(const f16x8*)(Bsm + (wn * 64 + n * 16 + lr) * BK + ks * 32 + koff);
#pragma unroll
      for (int m = 0; m < 4; ++m)
#pragma unroll
        for (int n = 0; n < 4; ++n)
          acc[m][n] = mfma16(af[m], bfr[n], acc[m][n]);
    }
    __syncthreads();
  }

#pragma unroll
  for (int m = 0; m < 4; ++m) {
#pragma unroll
    for (int r = 0; r < 4; ++r) {
      int grow = m0 + wm * 64 + m * 16 + lq * 4 + r;
      if (MTAIL && grow >= M) continue;
#pragma unroll
      for (int n = 0; n < 4; ++n) {
        int gcol = n0 + wn * 64 + n * 16 + lr;
        float v = acc[m][n][r];
        if (HAS_BIAS) v += bias[gcol];
        if (OUT_F16)
          ((u16*)Cp)[(size_t)grow * N + gcol] = f2h(v);
        else
          ((float*)Cp)[(size_t)grow * N + gcol] = v;
      }
    }
  }
}

// ---------------- fused attention (4 q-tiles per block, r8) -----------------
__global__ __launch_bounds__(256) void attn_fused(const u16* __restrict__ Q,
                                                  const u16* __restrict__ Kp,
                                                  const u16* __restrict__ Vp,
                                                  u16* __restrict__ Oa,
                                                  float scale) {
  __shared__ u16 Ksm[80][168];
  __shared__ u16 VT[160][104];
  __shared__ u16 Psm[4][16][96];
  const int tid = threadIdx.x, lane = tid & 63, wid = tid >> 6;
  const int lq = lane >> 4, lr = lane & 15, koff = lq << 3;
  const int qg = blockIdx.x, h = blockIdx.y, b = blockIdx.z;

  {
    u16x8 z = {0, 0, 0, 0, 0, 0, 0, 0};
    for (int i = tid; i < 80 * 168 / 8; i += 256) ((u16x8*)&Ksm[0][0])[i] = z;
    for (int i = tid; i < 160 * 104 / 8; i += 256) ((u16x8*)&VT[0][0])[i] = z;
    for (int i = tid; i < 4 * 16 * 96 / 8; i += 256) ((u16x8*)&Psm[0][0][0])[i] = z;
  }
  __syncthreads();

  const size_t kvbase = ((size_t)b * 77) * 1280 + (size_t)h * 160;
  for (int i = tid; i < 77 * 20; i += 256) {
    int r = i / 20, c8 = (i % 20) * 8;
    *(u16x8*)&Ksm[r][c8] = *(const u16x8*)(Kp + kvbase + (size_t)r * 1280 + c8);
  }
  for (int i = tid; i < 77 * 20; i += 256) {
    int r = i / 20, c8 = (i % 20) * 8;
    u16x8 v = *(const u16x8*)(Vp + kvbase + (size_t)r * 1280 + c8);
#pragma unroll
    for (int j = 0; j < 8; ++j) VT[c8 + j][r] = v[j];
  }
  __syncthreads();

  for (int it = 0; it < 4; ++it) {
    const int qt = qg * 4 + it;

    f16x8 qf[5];
    const int qrow = qt * 64 + wid * 16 + lr;
    const size_t qbase = ((size_t)b * 4096 + qrow) * 1280 + (size_t)h * 160;
#pragma unroll
    for (int ks = 0; ks < 5; ++ks)
      qf[ks] = *(const f16x8*)(Q + qbase + ks * 32 + koff);

    f32x4 sc[5];
#pragma unroll
    for (int nt = 0; nt < 5; ++nt) {
      sc[nt] = (f32x4){0.f, 0.f, 0.f, 0.f};
#pragma unroll
      for (int ks = 0; ks < 5; ++ks) {
        f16x8 kf = *(const f16x8*)&Ksm[nt * 16 + lr][ks * 32 + koff];
        sc[nt] = mfma16(qf[ks], kf, sc[nt]);
      }
    }

    float p[5][4];
#pragma unroll
    for (int r = 0; r < 4; ++r) {
      float mx = -1e30f;
#pragma unroll
      for (int nt = 0; nt < 5; ++nt) {
        float v = sc[nt][r] * scale;
        if (nt * 16 + lr >= 77) v = -1e30f;
        p[nt][r] = v;
        mx = fmaxf(mx, v);
      }
#pragma unroll
      for (int d = 1; d < 16; d <<= 1) mx = fmaxf(mx, __shfl_xor(mx, d));
      float sum = 0.f;
#pragma unroll
      for (int nt = 0; nt < 5; ++nt) {
        float e = __expf(p[nt][r] - mx);
        p[nt][r] = e;
        sum += e;
      }
#pragma unroll
      for (int d = 1; d < 16; d <<= 1) sum += __shfl_xor(sum, d);
      float inv = 1.f / sum;
#pragma unroll
      for (int nt = 0; nt < 5; ++nt) p[nt][r] *= inv;
    }

#pragma unroll
    for (int r = 0; r < 4; ++r)
#pragma unroll
      for (int nt = 0; nt < 5; ++nt)
        Psm[wid][lq * 4 + r][nt * 16 + lr] = f2h(p[nt][r]);

    f32x4 ov[10];
#pragma unroll
    for (int n2 = 0; n2 < 10; ++n2) ov[n2] = (f32x4){0.f, 0.f, 0.f, 0.f};
#pragma unroll
    for (int k2 = 0; k2 < 3; ++k2) {
      f16x8 pf = *(const f16x8*)&Psm[wid][lr][k2 * 32 + koff];
#pragma unroll
      for (int n2 = 0; n2 < 10; ++n2) {
        f16x8 vf = *(const f16x8*)&VT[n2 * 16 + lr][k2 * 32 + koff];
        ov[n2] = mfma16(pf, vf, ov[n2]);
      }
    }

    const size_t obase =
        ((size_t)b * 4096 + (size_t)qt * 64 + wid * 16 + lq * 4) * 1280 +
        (size_t)h * 160;
#pragma unroll
    for (int r = 0; r < 4; ++r)
#pragma unroll
      for (int n2 = 0; n2 < 10; ++n2)
        Oa[obase + (size_t)r * 1280 + n2 * 16 + lr] = f2h(ov[n2][r]);
  }
}

// ---------------- host orchestration ----------------------------------------
extern "C" void kernel_launch(void* const* d_in, const int* in_sizes, int n_in,
                              void* d_out, int out_size, void* d_ws,
                              size_t ws_size, hipStream_t stream) {
  (void)in_sizes; (void)n_in; (void)out_size; (void)ws_size;
  const float* hs  = (const float*)d_in[0];
  const float* enc = (const float*)d_in[1];
  const float* Wq  = (const float*)d_in[2];
  const float* Wk  = (const float*)d_in[3];
  const float* Wv  = (const float*)d_in[4];
  const float* Wo  = (const float*)d_in[5];
  const float* bo  = (const float*)d_in[6];
  float* out = (float*)d_out;

  const int B = 16, S = 4096, SKV = 77, HID = 1280, CDIM = 768;
  const int MQ = B * S;
  const int MKV = B * SKV;

  char* ws = (char*)d_ws;
  size_t off = 0;
  auto alloc = [&](size_t bytes) -> char* {
    char* p = ws + off;
    off += (bytes + 255) & ~(size_t)255;
    return p;
  };
  u16* hs_h  = (u16*)alloc((size_t)MQ * HID * 2);
  u16* q_h   = (u16*)alloc((size_t)MQ * HID * 2);
  u16* enc_h = (u16*)alloc((size_t)MKV * CDIM * 2);
  u16* wq_h  = (u16*)alloc((size_t)HID * HID * 2);
  u16* wk_h  = (u16*)alloc((size_t)HID * CDIM * 2);
  u16* wv_h  = (u16*)alloc((size_t)HID * CDIM * 2);
  u16* wo_h  = (u16*)alloc((size_t)HID * HID * 2);
  u16* k_h   = (u16*)alloc((size_t)MKV * HID * 2);
  u16* v_h   = (u16*)alloc((size_t)MKV * HID * 2);
  u16* attn_h = hs_h;  // hs_h dead after Q projection

  auto cvt = [&](const float* src, u16* dst, long n) {
    long n8 = n / 8;
    int blocks = (int)((n8 + 255) / 256);
    if (blocks > 2048) blocks = 2048;
    cvt_f32_f16<<<blocks, 256, 0, stream>>>(src, dst, n8);
  };
  cvt(hs,  hs_h,  (long)MQ * HID);
  cvt(enc, enc_h, (long)MKV * CDIM);
  cvt(Wq,  wq_h,  (long)HID * HID);
  cvt(Wk,  wk_h,  (long)HID * CDIM);
  cvt(Wv,  wv_h,  (long)HID * CDIM);
  cvt(Wo,  wo_h,  (long)HID * HID);

  // K/V projections (small, tail): 128^2 kernel
  gemm_bt<1, 0, 1><<<dim3(10, 10), 256, 0, stream>>>(enc_h, wk_h, k_h, nullptr, MKV, HID, CDIM);
  gemm_bt<1, 0, 1><<<dim3(10, 10), 256, 0, stream>>>(enc_h, wv_h, v_h, nullptr, MKV, HID, CDIM);

  // Q projection: 256^2 8-phase kernel. grid = (M/256)*(N/256) = 1280
  const int grid_big = (MQ / 256) * (HID / 256);
  gemm_8ph<1, 0><<<dim3(grid_big), dim3(512), 131072, stream>>>(
      hs_h, wq_h, q_h, nullptr, MQ, HID, HID);

  const float scale = 1.0f / sqrtf(160.0f);
  attn_fused<<<dim3(16, 8, 16), 256, 0, stream>>>(q_h, k_h, v_h, attn_h, scale);

  // output projection (+bias, f32 out)
  gemm_8ph<0, 1><<<dim3(grid_big), dim3(512), 131072, stream>>>(
      attn_h, wo_h, out, bo, MQ, HID, HID);
}